// Round 6
// baseline (2263.090 us; speedup 1.0000x reference)
//
#include <hip/hip_runtime.h>
#include <math.h>

// ============================================================================
// R6: R5's scalar diagnostic pipeline with FLOAT32 output (the R4/R5 bug:
// identical absmax 4.5625 across two different pipelines = permuted-but-right
// values = output buffer is f32, not bf16; "(bf16" in the test label is
// frozen text, and threshold 0.070625 == 2% * max|ref| = f32 mode).
// Inputs f32 (confirmed R4: finite output).
//
// Pipeline:
//   1. sgemm: Qraw = a@Wq (f32), Kraw = x@Wk (f32), Vbf = a@Wv (bf16)
//   2. rope_q / rope_k (f32 math, mirrors reference expression exactly)
//   3. scores32: f64-accumulated q.k per branch, f32 scale (/sqrt(C)),
//      branch max + multi-hot tie mask, causal -inf -> M (f32), Mask (u8)
//   4. rowstats: rowmax + 1/sum(exp) over s
//   5. pv: y[t,c] = sum_s p(t,s) * sum_{n in mask} v[n,s,c]   (scalar)
//   6. sgemm: out = Y @ Wo (f32 out -> d_out)
//
// ws layout (104,890,368 B):
//   0         Qraw f32 33.5MB   -> overlaid by M f32 (dead after rope_q)
//   33554432  Qp   f32 33.5MB
//   67108864  Kraw f32  8.4MB   -> overlaid by Mask u8 (dead after rope_k)
//   75497472  Kp   f32  8.4MB
//   83886080  Vbf  u16 16.8MB
//   100663296 Y    u16  4.2MB
//   104857600 Rm/Rz f32 2x16KB
// ============================================================================

#define T_ 2048
#define C_ 512
#define NB_ 4

typedef unsigned short u16;
typedef unsigned char u8;

__device__ __forceinline__ float bf2f(u16 u) {
  union { unsigned int i; float f; } v; v.i = ((unsigned int)u) << 16; return v.f;
}
__device__ __forceinline__ u16 f2bf(float f) {  // round-to-nearest-even
  union { float f; unsigned int i; } v; v.f = f;
  unsigned int u = v.i;
  return (u16)((u + 0x7fffu + ((u >> 16) & 1u)) >> 16);
}

// ---------------------------------------------------------------------------
// Scalar tiled GEMM: out[M,N] = A[M,K] @ W[K,N]. 64x64 tile, 16 k-chunk,
// 16x16 threads, 4x4 outputs/thread. AT_BF16: A is bf16. OT_BF16: out bf16.
// ---------------------------------------------------------------------------
template <int AT_BF16, int OT_BF16>
__global__ __launch_bounds__(256) void sgemm(const void* __restrict__ Ap,
                                             const float* __restrict__ W,
                                             void* __restrict__ outp,
                                             const int N, const int K) {
  __shared__ float As[64][17];
  __shared__ float Ws[16][65];
  const int tid = threadIdx.x;
  const int m0 = blockIdx.y << 6, n0 = blockIdx.x << 6;
  const int ty = tid >> 4, tx = tid & 15;
  float acc[4][4] = {{0.f}};
  for (int kk = 0; kk < K; kk += 16) {
    {
      const int row = tid >> 2, c4 = (tid & 3) << 2;
      if (AT_BF16) {
        const u16* A = (const u16*)Ap;
        ushort4 v = *(const ushort4*)(&A[(size_t)(m0 + row) * K + kk + c4]);
        As[row][c4 + 0] = bf2f(v.x); As[row][c4 + 1] = bf2f(v.y);
        As[row][c4 + 2] = bf2f(v.z); As[row][c4 + 3] = bf2f(v.w);
      } else {
        const float* A = (const float*)Ap;
        float4 v = *(const float4*)(&A[(size_t)(m0 + row) * K + kk + c4]);
        As[row][c4 + 0] = v.x; As[row][c4 + 1] = v.y;
        As[row][c4 + 2] = v.z; As[row][c4 + 3] = v.w;
      }
      const int wr = tid >> 4, wc4 = (tid & 15) << 2;
      float4 wv = *(const float4*)(&W[(size_t)(kk + wr) * N + n0 + wc4]);
      Ws[wr][wc4 + 0] = wv.x; Ws[wr][wc4 + 1] = wv.y;
      Ws[wr][wc4 + 2] = wv.z; Ws[wr][wc4 + 3] = wv.w;
    }
    __syncthreads();
#pragma unroll
    for (int kc = 0; kc < 16; ++kc) {
      float a[4], w[4];
#pragma unroll
      for (int i = 0; i < 4; ++i) a[i] = As[(ty << 2) + i][kc];
#pragma unroll
      for (int j = 0; j < 4; ++j) w[j] = Ws[kc][(tx << 2) + j];
#pragma unroll
      for (int i = 0; i < 4; ++i)
#pragma unroll
        for (int j = 0; j < 4; ++j) acc[i][j] += a[i] * w[j];
    }
    __syncthreads();
  }
#pragma unroll
  for (int i = 0; i < 4; ++i)
#pragma unroll
    for (int j = 0; j < 4; ++j) {
      const size_t idx = (size_t)(m0 + (ty << 2) + i) * N + n0 + (tx << 2) + j;
      if (OT_BF16) ((u16*)outp)[idx] = f2bf(acc[i][j]);
      else ((float*)outp)[idx] = acc[i][j];
    }
}

// ---------------------------------------------------------------------------
// RoPE (mirrors reference f32 expressions). One block per (b,n,t) [q] or
// (b,t) [k]; 256 threads = 256 pairs.
// ---------------------------------------------------------------------------
__global__ __launch_bounds__(256) void rope_q(const float* __restrict__ Qraw,
                                              const float* __restrict__ cosT,
                                              const float* __restrict__ sinT,
                                              float* __restrict__ Qp) {
  const int bid = blockIdx.x;
  const int t = bid & (T_ - 1);
  const int n = (bid >> 11) & 3;
  const int b = bid >> 13;
  const int i = threadIdx.x;
  const float2 xv = *(const float2*)(
      &Qraw[((size_t)((b << 11) + t)) * (NB_ * C_) + n * C_ + 2 * i]);
  const float cf = cosT[(t << 8) + i], sf = sinT[(t << 8) + i];
  const float y1 = xv.x * cf - xv.y * sf;
  const float y2 = xv.x * sf + xv.y * cf;
  float2* dst = (float2*)(
      &Qp[((size_t)((b * NB_ + n) * T_ + t)) * C_ + 2 * i]);
  *dst = make_float2(y1, y2);
}

__global__ __launch_bounds__(256) void rope_k(const float* __restrict__ Kraw,
                                              const float* __restrict__ cosT,
                                              const float* __restrict__ sinT,
                                              float* __restrict__ Kp) {
  const int bid = blockIdx.x;
  const int t = bid & (T_ - 1);
  const int b = bid >> 11;
  const int i = threadIdx.x;
  const float2 xv =
      *(const float2*)(&Kraw[((size_t)((b << 11) + t)) * C_ + 2 * i]);
  const float cf = cosT[(t << 8) + i], sf = sinT[(t << 8) + i];
  const float y1 = xv.x * cf - xv.y * sf;
  const float y2 = xv.x * sf + xv.y * cf;
  float2* dst = (float2*)(&Kp[((size_t)((b << 11) + t)) * C_ + 2 * i]);
  *dst = make_float2(y1, y2);
}

// ---------------------------------------------------------------------------
// Scores: 32x32 (t,s) tile per block, lower-tri only. f64 accumulation of
// q.k per branch; scale /sqrt(C) in f32; branch max + multi-hot tie mask.
// ---------------------------------------------------------------------------
__global__ __launch_bounds__(256) void scores32(const float* __restrict__ Qp,
                                                const float* __restrict__ Kp,
                                                float* __restrict__ M,
                                                u8* __restrict__ Mask) {
  const int ss = blockIdx.x, tt = blockIdx.y, b = blockIdx.z;
  if (ss > tt) return;
  __shared__ float Qs[NB_][32][33];
  __shared__ float Ks[32][33];
  const int tid = threadIdx.x;
  const int t0 = tt << 5, s0 = ss << 5;
  const int trow = tid >> 3, sc4 = (tid & 7) << 2;
  double acc[NB_][4];
#pragma unroll
  for (int n = 0; n < NB_; ++n)
#pragma unroll
    for (int j = 0; j < 4; ++j) acc[n][j] = 0.0;

  const int qn = tid >> 6, qrow = (tid >> 1) & 31, qh = (tid & 1) << 4;
  const int krow = tid >> 3, kc4 = (tid & 7) << 2;
  for (int kk = 0; kk < C_; kk += 32) {
#pragma unroll
    for (int u = 0; u < 4; ++u) {
      float4 v = *(const float4*)(
          &Qp[((size_t)((b * NB_ + qn) * T_ + t0 + qrow)) * C_ + kk + qh + (u << 2)]);
      Qs[qn][qrow][qh + (u << 2) + 0] = v.x;
      Qs[qn][qrow][qh + (u << 2) + 1] = v.y;
      Qs[qn][qrow][qh + (u << 2) + 2] = v.z;
      Qs[qn][qrow][qh + (u << 2) + 3] = v.w;
    }
    {
      float4 v = *(const float4*)(
          &Kp[((size_t)((b << 11) + s0 + krow)) * C_ + kk + kc4]);
      Ks[krow][kc4 + 0] = v.x; Ks[krow][kc4 + 1] = v.y;
      Ks[krow][kc4 + 2] = v.z; Ks[krow][kc4 + 3] = v.w;
    }
    __syncthreads();
#pragma unroll 4
    for (int kc = 0; kc < 32; ++kc) {
      float kv[4];
#pragma unroll
      for (int j = 0; j < 4; ++j) kv[j] = Ks[sc4 + j][kc];
#pragma unroll
      for (int n = 0; n < NB_; ++n) {
        const float qv = Qs[n][trow][kc];
#pragma unroll
        for (int j = 0; j < 4; ++j) acc[n][j] += (double)qv * (double)kv[j];
      }
    }
    __syncthreads();
  }
  const int t = t0 + trow;
#pragma unroll
  for (int j = 0; j < 4; ++j) {
    const int s = s0 + sc4 + j;
    float a0 = (float)acc[0][j] / 22.627416997969522f;
    float a1 = (float)acc[1][j] / 22.627416997969522f;
    float a2 = (float)acc[2][j] / 22.627416997969522f;
    float a3 = (float)acc[3][j] / 22.627416997969522f;
    float m = fmaxf(fmaxf(a0, a1), fmaxf(a2, a3));
    u8 msk = (u8)((a0 == m) | ((a1 == m) << 1) | ((a2 == m) << 2) |
                  ((a3 == m) << 3));
    if (s > t) { m = -__builtin_inff(); msk = 0; }
    const size_t idx = ((size_t)((b << 11) + t) << 11) + s;
    M[idx] = m;
    Mask[idx] = msk;
  }
}

// ---------------------------------------------------------------------------
// Row softmax stats: one wave per (b,t) row; 4 waves per block.
// ---------------------------------------------------------------------------
__global__ __launch_bounds__(256) void rowstats(const float* __restrict__ M,
                                                float* __restrict__ Rm,
                                                float* __restrict__ Rz) {
  const int r = (blockIdx.x << 2) + (threadIdx.x >> 6);
  const int lane = threadIdx.x & 63;
  const int t = r & (T_ - 1);
  const float* row = M + ((size_t)r << 11);
  float m = -__builtin_inff();
  for (int s = lane; s <= t; s += 64) m = fmaxf(m, row[s]);
#pragma unroll
  for (int off = 32; off; off >>= 1) m = fmaxf(m, __shfl_xor(m, off));
  float z = 0.f;
  for (int s = lane; s <= t; s += 64) z += expf(row[s] - m);
#pragma unroll
  for (int off = 32; off; off >>= 1) z += __shfl_xor(z, off);
  if (lane == 0) { Rm[r] = m; Rz[r] = 1.f / z; }
}

// ---------------------------------------------------------------------------
// Routed PV, scalar: block per (b,t); 256 threads cover 512 channels (2 each).
// y[t,c] = sum_{s<=t} p(t,s) * sum_{n in mask(t,s)} v[b,s,n*512+c]
// ---------------------------------------------------------------------------
__global__ __launch_bounds__(256) void pv_scalar(const float* __restrict__ M,
                                                 const u8* __restrict__ Mask,
                                                 const float* __restrict__ Rm,
                                                 const float* __restrict__ Rz,
                                                 const u16* __restrict__ Vbf,
                                                 u16* __restrict__ Y) {
  const int bid = blockIdx.x;          // b*2048 + t
  const int t = bid & (T_ - 1);
  const int b = bid >> 11;
  const int tid = threadIdx.x;
  const float rm = Rm[bid], rz = Rz[bid];
  const float* mrow = M + ((size_t)bid << 11);
  const u8* krow = Mask + ((size_t)bid << 11);
  float acc0 = 0.f, acc1 = 0.f;
  for (int s = 0; s <= t; ++s) {
    const float p = expf(mrow[s] - rm) * rz;
    const u8 mk = krow[s];
    const u16* vrow = Vbf + ((size_t)((b << 11) + s)) * (NB_ * C_);
#pragma unroll
    for (int n = 0; n < NB_; ++n) {
      if ((mk >> n) & 1) {
        acc0 += p * bf2f(vrow[n * C_ + tid]);
        acc1 += p * bf2f(vrow[n * C_ + tid + 256]);
      }
    }
  }
  Y[((size_t)bid << 9) + tid] = f2bf(acc0);
  Y[((size_t)bid << 9) + tid + 256] = f2bf(acc1);
}

// ---------------------------------------------------------------------------
extern "C" void kernel_launch(void* const* d_in, const int* in_sizes, int n_in,
                              void* d_out, int out_size, void* d_ws,
                              size_t ws_size, hipStream_t stream) {
  (void)in_sizes; (void)n_in; (void)out_size; (void)ws_size;
  const float* a    = (const float*)d_in[0];
  const float* x    = (const float*)d_in[1];
  const float* Wq   = (const float*)d_in[2];
  const float* Wk   = (const float*)d_in[3];
  const float* Wv   = (const float*)d_in[4];
  const float* Wo   = (const float*)d_in[5];
  const float* cosT = (const float*)d_in[6];
  const float* sinT = (const float*)d_in[7];

  char* w = (char*)d_ws;
  float* Qraw = (float*)(w + 0);          // 33.5MB -> M after rope_q
  float* Qp   = (float*)(w + 33554432);   // 33.5MB
  float* Kraw = (float*)(w + 67108864);   //  8.4MB -> Mask after rope_k
  float* Kp   = (float*)(w + 75497472);   //  8.4MB
  u16*   Vbf  = (u16*)(w + 83886080);     // 16.8MB
  u16*   Y    = (u16*)(w + 100663296);    //  4.2MB
  float* Rm   = (float*)(w + 104857600);
  float* Rz   = (float*)(w + 104873984);  // end 104,890,368
  float* M    = Qraw;
  u8*    Mask = (u8*)Kraw;

  const dim3 blk(256);
  sgemm<0, 0><<<dim3(32, 64), blk, 0, stream>>>(a, Wq, (void*)Qraw, 2048, 512);
  sgemm<0, 0><<<dim3(8, 64), blk, 0, stream>>>(x, Wk, (void*)Kraw, 512, 512);
  sgemm<0, 1><<<dim3(32, 64), blk, 0, stream>>>(a, Wv, (void*)Vbf, 2048, 512);
  rope_q<<<dim3(2 * NB_ * T_), blk, 0, stream>>>(Qraw, cosT, sinT, Qp);
  rope_k<<<dim3(2 * T_), blk, 0, stream>>>(Kraw, cosT, sinT, Kp);
  scores32<<<dim3(64, 64, 2), blk, 0, stream>>>(Qp, Kp, M, Mask);
  rowstats<<<dim3(1024), blk, 0, stream>>>(M, Rm, Rz);
  pv_scalar<<<dim3(2 * T_), blk, 0, stream>>>(M, Mask, Rm, Rz, Vbf, Y);
  sgemm<1, 0><<<dim3(8, 64), blk, 0, stream>>>(Y, Wo, d_out, 512, 512);
}

// Round 7
// 741.606 us; speedup vs baseline: 3.0516x; 3.0516x over previous
//
#include <hip/hip_runtime.h>
#include <math.h>

// ============================================================================
// R7: full MFMA pipeline (validated semantics from R6 scalar anchor; R4's
// MFMA math was already correct — its only bug was storing bf16 into the
// f32 output buffer). Inputs f32, output f32.
//
// * Q/K projections: f32 operands split to bf16 hi/lo in LDS, 3-term MFMA
//   (ah.wh + al.wh + ah.wl), fused f32 RoPE epilogue via __shfl_xor(acc,1)
//   column pairing; store hi/lo Qcat/Kcat for split-precision QK^T.
// * scores_k: att = qh.kh + ql.kh + qh.kl (K=1536 MFMA, err ~1e-6) ->
//   branch max (bf16 M) + multi-hot tie mask (u8) from f32 accumulators.
// * pv_k: y = sum_n P_n @ V_n, per-branch masked P built in LDS.
// * Final Y @ Wo -> f32 d_out.
// ws use: 83,918,848 B (M over Vraw, Y over Qcat head; stream-ordered).
// ============================================================================

#define B_ 2
#define T_ 2048
#define C_ 512
#define NB_ 4
#define C2_ 1024  // hi|lo row width for Qcat/Kcat

typedef unsigned short u16;
typedef unsigned char u8;
using short8 = __attribute__((ext_vector_type(8))) short;
using bf16x8 = __attribute__((ext_vector_type(8))) __bf16;
using f32x4  = __attribute__((ext_vector_type(4))) float;

__device__ __forceinline__ float bf2f(u16 u) {
  union { unsigned int i; float f; } v; v.i = ((unsigned int)u) << 16; return v.f;
}
__device__ __forceinline__ u16 f2bf(float f) {  // round-to-nearest-even
  union { float f; unsigned int i; } v; v.f = f;
  unsigned int u = v.i;
  return (u16)((u + 0x7fffu + ((u >> 16) & 1u)) >> 16);
}
__device__ __forceinline__ f32x4 mfma16x16x32(short8 a, short8 b, f32x4 c) {
  return __builtin_amdgcn_mfma_f32_16x16x32_bf16(
      __builtin_bit_cast(bf16x8, a), __builtin_bit_cast(bf16x8, b), c, 0, 0, 0);
}
__device__ __forceinline__ void split8(const float* s, uint4& hi, uint4& lo) {
  u16 h[8], l[8];
#pragma unroll
  for (int j = 0; j < 8; ++j) {
    h[j] = f2bf(s[j]);
    l[j] = f2bf(s[j] - bf2f(h[j]));
  }
  hi.x = h[0] | ((unsigned)h[1] << 16); hi.y = h[2] | ((unsigned)h[3] << 16);
  hi.z = h[4] | ((unsigned)h[5] << 16); hi.w = h[6] | ((unsigned)h[7] << 16);
  lo.x = l[0] | ((unsigned)l[1] << 16); lo.y = l[2] | ((unsigned)l[3] << 16);
  lo.z = l[4] | ((unsigned)l[5] << 16); lo.w = l[6] | ((unsigned)l[7] << 16);
}

// ---------------------------------------------------------------------------
// Split-precision 64x64 GEMM with fused RoPE epilogue.
// A[M,K] f32, W[K,N] f32. acc = ah.wh + al.wh + ah.wl (f32 MFMA acc).
// MODE 1: +1/sqrt(C) scale -> Qcat (B,NB,T,[hi512|lo512]).
// MODE 2: -> Kcat (B*T,[hi512|lo512]).
// ---------------------------------------------------------------------------
template <int MODE>
__global__ __launch_bounds__(256) void gemm_qk(const float* __restrict__ A,
                                               const float* __restrict__ W,
                                               u16* __restrict__ out,
                                               const float* __restrict__ cosT,
                                               const float* __restrict__ sinT,
                                               const int N, const int K) {
  __shared__ u16 Ah[64][32], Al[64][32];
  __shared__ u16 Bh[64][32], Bl[64][32];  // [n][k]
  const int tid = threadIdx.x;
  const int wave = tid >> 6, lane = tid & 63;
  const int m0 = blockIdx.y << 6, n0 = blockIdx.x << 6;
  const f32x4 zero = {0.f, 0.f, 0.f, 0.f};
  f32x4 acc[4] = {zero, zero, zero, zero};
  const int row = tid & 63, k8 = (tid >> 6) << 3;
  const int lrow = lane & 15, lk = (lane >> 4) << 3;
  for (int kk = 0; kk < K; kk += 32) {
    float av[8];
    *(float4*)(av) = *(const float4*)(&A[(size_t)(m0 + row) * K + kk + k8]);
    *(float4*)(av + 4) = *(const float4*)(&A[(size_t)(m0 + row) * K + kk + k8 + 4]);
    uint4 hi, lo;
    split8(av, hi, lo);
    *(uint4*)(&Ah[row][k8]) = hi;
    *(uint4*)(&Al[row][k8]) = lo;
    float wv[8];
#pragma unroll
    for (int j = 0; j < 8; ++j)
      wv[j] = W[(size_t)(kk + k8 + j) * N + n0 + row];
    split8(wv, hi, lo);
    *(uint4*)(&Bh[row][k8]) = hi;
    *(uint4*)(&Bl[row][k8]) = lo;
    __syncthreads();
    short8 ah = *(const short8*)(&Ah[(wave << 4) + lrow][lk]);
    short8 al = *(const short8*)(&Al[(wave << 4) + lrow][lk]);
#pragma unroll
    for (int ns = 0; ns < 4; ++ns) {
      short8 bh = *(const short8*)(&Bh[(ns << 4) + lrow][lk]);
      short8 bl = *(const short8*)(&Bl[(ns << 4) + lrow][lk]);
      acc[ns] = mfma16x16x32(ah, bh, acc[ns]);
      acc[ns] = mfma16x16x32(al, bh, acc[ns]);
      acc[ns] = mfma16x16x32(ah, bl, acc[ns]);
    }
    __syncthreads();
  }
  const int r0 = m0 + (wave << 4) + ((lane >> 4) << 2);
  const int cb = n0 + (lane & 15);
#pragma unroll
  for (int ns = 0; ns < 4; ++ns) {
#pragma unroll
    for (int r = 0; r < 4; ++r) {
      const int rg = r0 + r;
      const int cg = cb + (ns << 4);
      float v = acc[ns][r];
      float pv = __shfl_xor(v, 1);  // partner column of the RoPE pair
      const int t = rg & (T_ - 1);
      const int c = (MODE == 1) ? (cg & (C_ - 1)) : cg;
      const int i = c >> 1;
      const float cf = cosT[(t << 8) + i];
      const float sf = sinT[(t << 8) + i];
      float x1 = (lane & 1) ? pv : v;
      float x2 = (lane & 1) ? v : pv;
      float y = (lane & 1) ? (x1 * sf + x2 * cf) : (x1 * cf - x2 * sf);
      if (MODE == 1) y *= 0.044194173824159216f;  // 1/sqrt(512)
      const u16 hi = f2bf(y);
      const u16 lo = f2bf(y - bf2f(hi));
      size_t rowoff;
      if (MODE == 1) {
        const int b = rg >> 11, n = cg >> 9;
        rowoff = ((size_t)((b * NB_ + n) * T_ + t)) * C2_;
      } else {
        rowoff = (size_t)rg * C2_;
      }
      out[rowoff + c] = hi;
      out[rowoff + C_ + c] = lo;
    }
  }
}

// ---------------------------------------------------------------------------
// Plain hi-only GEMM: A f32 (AF32=1) or bf16, W f32; out bf16 or f32 (OF32).
// ---------------------------------------------------------------------------
template <int AF32, int OF32>
__global__ __launch_bounds__(256) void gemm_hi(const void* __restrict__ Ap,
                                               const float* __restrict__ W,
                                               void* __restrict__ outp,
                                               const int N, const int K) {
  __shared__ u16 As[64][32];
  __shared__ u16 Bs[64][32];
  const int tid = threadIdx.x;
  const int wave = tid >> 6, lane = tid & 63;
  const int m0 = blockIdx.y << 6, n0 = blockIdx.x << 6;
  const f32x4 zero = {0.f, 0.f, 0.f, 0.f};
  f32x4 acc[4] = {zero, zero, zero, zero};
  const int row = tid & 63, k8 = (tid >> 6) << 3;
  const int lrow = lane & 15, lk = (lane >> 4) << 3;
  for (int kk = 0; kk < K; kk += 32) {
    if (AF32) {
      const float* A = (const float*)Ap;
      float av[8];
      *(float4*)(av) = *(const float4*)(&A[(size_t)(m0 + row) * K + kk + k8]);
      *(float4*)(av + 4) = *(const float4*)(&A[(size_t)(m0 + row) * K + kk + k8 + 4]);
      uint4 hi;
      hi.x = f2bf(av[0]) | ((unsigned)f2bf(av[1]) << 16);
      hi.y = f2bf(av[2]) | ((unsigned)f2bf(av[3]) << 16);
      hi.z = f2bf(av[4]) | ((unsigned)f2bf(av[5]) << 16);
      hi.w = f2bf(av[6]) | ((unsigned)f2bf(av[7]) << 16);
      *(uint4*)(&As[row][k8]) = hi;
    } else {
      const u16* A = (const u16*)Ap;
      *(uint4*)(&As[row][k8]) =
          *(const uint4*)(&A[(size_t)(m0 + row) * K + kk + k8]);
    }
    uint4 hi;
    {
      float w0 = W[(size_t)(kk + k8 + 0) * N + n0 + row];
      float w1 = W[(size_t)(kk + k8 + 1) * N + n0 + row];
      float w2 = W[(size_t)(kk + k8 + 2) * N + n0 + row];
      float w3 = W[(size_t)(kk + k8 + 3) * N + n0 + row];
      float w4 = W[(size_t)(kk + k8 + 4) * N + n0 + row];
      float w5 = W[(size_t)(kk + k8 + 5) * N + n0 + row];
      float w6 = W[(size_t)(kk + k8 + 6) * N + n0 + row];
      float w7 = W[(size_t)(kk + k8 + 7) * N + n0 + row];
      hi.x = f2bf(w0) | ((unsigned)f2bf(w1) << 16);
      hi.y = f2bf(w2) | ((unsigned)f2bf(w3) << 16);
      hi.z = f2bf(w4) | ((unsigned)f2bf(w5) << 16);
      hi.w = f2bf(w6) | ((unsigned)f2bf(w7) << 16);
    }
    *(uint4*)(&Bs[row][k8]) = hi;
    __syncthreads();
    short8 af = *(const short8*)(&As[(wave << 4) + lrow][lk]);
#pragma unroll
    for (int ns = 0; ns < 4; ++ns) {
      short8 bf = *(const short8*)(&Bs[(ns << 4) + lrow][lk]);
      acc[ns] = mfma16x16x32(af, bf, acc[ns]);
    }
    __syncthreads();
  }
  const int r0 = m0 + (wave << 4) + ((lane >> 4) << 2);
  const int cb = n0 + (lane & 15);
#pragma unroll
  for (int ns = 0; ns < 4; ++ns) {
#pragma unroll
    for (int r = 0; r < 4; ++r) {
      const size_t idx = (size_t)(r0 + r) * N + cb + (ns << 4);
      if (OF32) ((float*)outp)[idx] = acc[ns][r];
      else ((u16*)outp)[idx] = f2bf(acc[ns][r]);
    }
  }
}

// ---------------------------------------------------------------------------
// Vraw (B,T,NB*C) bf16 -> VT (B,NB,C,T) tiled transpose, 64x64 tiles.
// ---------------------------------------------------------------------------
__global__ __launch_bounds__(256) void transpose_v_k(const u16* __restrict__ Vraw,
                                                     u16* __restrict__ VT) {
  const int bid = blockIdx.x;
  const int ct = bid & 7;
  const int ttile = (bid >> 3) & 31;
  const int n = (bid >> 8) & 3;
  const int b = bid >> 10;
  __shared__ u16 tile[64][68];
  const int tid = threadIdx.x;
  const int rr = tid >> 4;
  const int cc = (tid & 15) << 2;
  const int t0 = ttile << 6, c0 = ct << 6;
#pragma unroll
  for (int it = 0; it < 4; ++it) {
    const int r = (it << 4) + rr;
    *(ushort4*)(&tile[r][cc]) = *(const ushort4*)(
        &Vraw[((size_t)((b << 11) + t0 + r)) * (NB_ * C_) + n * C_ + c0 + cc]);
  }
  __syncthreads();
#pragma unroll
  for (int it = 0; it < 4; ++it) {
    const int c = (it << 4) + rr;
    ushort4 w;
    w.x = tile[cc + 0][c]; w.y = tile[cc + 1][c];
    w.z = tile[cc + 2][c]; w.w = tile[cc + 3][c];
    *(ushort4*)(&VT[((size_t)((b * NB_ + n) * C_ + c0 + c)) * T_ + t0 + cc]) = w;
  }
}

// ---------------------------------------------------------------------------
// Scores: per lower-tri 64x64 (t,s) tile, 4 branches, split K=3*512:
// qh.kh + ql.kh + qh.kl. Branch max + multi-hot tie mask from f32 acc,
// causal -inf. Writes M (bf16) and Mask (u8).
// ---------------------------------------------------------------------------
__global__ __launch_bounds__(256) void scores_k(const u16* __restrict__ Qcat,
                                                const u16* __restrict__ Kcat,
                                                u16* __restrict__ Mout,
                                                u8* __restrict__ Mask) {
  const int ss = blockIdx.x, tt = blockIdx.y, b = blockIdx.z;
  if (ss > tt) return;
  __shared__ u16 Qs[NB_][64][32];
  __shared__ u16 Ks[64][32];
  const int tid = threadIdx.x;
  const int wave = tid >> 6, lane = tid & 63;
  const int t0 = tt << 6, s0 = ss << 6;
  const f32x4 zero = {0.f, 0.f, 0.f, 0.f};
  f32x4 acc[NB_][4];
  for (int n = 0; n < NB_; ++n)
    for (int j = 0; j < 4; ++j) acc[n][j] = zero;
  const int row = tid & 63, k8 = (tid >> 6) << 3;
  const int lrow = lane & 15, lk = (lane >> 4) << 3;
  for (int seg = 0; seg < 3; ++seg) {
    const int qoff = (seg == 1) ? C_ : 0;  // seg1 uses q_lo
    const int koff = (seg == 2) ? C_ : 0;  // seg2 uses k_lo
    for (int kk = 0; kk < C_; kk += 32) {
#pragma unroll
      for (int n = 0; n < NB_; ++n) {
        *(uint4*)(&Qs[n][row][k8]) = *(const uint4*)(
            &Qcat[((size_t)((b * NB_ + n) * T_ + t0 + row)) * C2_ + qoff + kk + k8]);
      }
      *(uint4*)(&Ks[row][k8]) = *(const uint4*)(
          &Kcat[((size_t)((b << 11) + s0 + row)) * C2_ + koff + kk + k8]);
      __syncthreads();
      short8 af[NB_];
#pragma unroll
      for (int n = 0; n < NB_; ++n)
        af[n] = *(const short8*)(&Qs[n][(wave << 4) + lrow][lk]);
#pragma unroll
      for (int ns = 0; ns < 4; ++ns) {
        short8 bf = *(const short8*)(&Ks[(ns << 4) + lrow][lk]);
#pragma unroll
        for (int n = 0; n < NB_; ++n)
          acc[n][ns] = mfma16x16x32(af[n], bf, acc[n][ns]);
      }
      __syncthreads();
    }
  }
  const int tb = t0 + (wave << 4) + ((lane >> 4) << 2);
  const int sb = s0 + (lane & 15);
#pragma unroll
  for (int ns = 0; ns < 4; ++ns) {
#pragma unroll
    for (int r = 0; r < 4; ++r) {
      const int t = tb + r, s = sb + (ns << 4);
      float a0 = acc[0][ns][r], a1 = acc[1][ns][r];
      float a2 = acc[2][ns][r], a3 = acc[3][ns][r];
      float m = fmaxf(fmaxf(a0, a1), fmaxf(a2, a3));
      u8 msk = (u8)((a0 == m) | ((a1 == m) << 1) | ((a2 == m) << 2) |
                    ((a3 == m) << 3));
      if (s > t) { m = -__builtin_inff(); msk = 0; }
      const size_t idx = (size_t)b * T_ * T_ + (size_t)t * T_ + s;
      Mout[idx] = f2bf(m);
      Mask[idx] = msk;
    }
  }
}

// ---------------------------------------------------------------------------
// Per-row softmax stats from bf16 M: rowmax, 1/sum(exp). One wave per (b,t).
// ---------------------------------------------------------------------------
__global__ __launch_bounds__(256) void rowstats_k(const u16* __restrict__ Mb,
                                                  float* __restrict__ Rm,
                                                  float* __restrict__ Rz) {
  const int r = (blockIdx.x << 2) + (threadIdx.x >> 6);
  const int lane = threadIdx.x & 63;
  const int b = r >> 11, t = r & (T_ - 1);
  const u16* row = Mb + (size_t)b * T_ * T_ + (size_t)t * T_;
  float m = -__builtin_inff();
  for (int s = lane; s <= t; s += 64) m = fmaxf(m, bf2f(row[s]));
#pragma unroll
  for (int off = 32; off; off >>= 1) m = fmaxf(m, __shfl_xor(m, off));
  float z = 0.f;
  for (int s = lane; s <= t; s += 64) z += expf(bf2f(row[s]) - m);
#pragma unroll
  for (int off = 32; off; off >>= 1) z += __shfl_xor(z, off);
  if (lane == 0) { Rm[r] = m; Rz[r] = 1.f / z; }
}

// ---------------------------------------------------------------------------
// Routed PV: y = sum_n P_n @ V_n with per-branch masked P built in LDS from
// bf16 M + mask. 64 t-rows x 64 c-cols per block, causal s-chunks of 32.
// ---------------------------------------------------------------------------
__global__ __launch_bounds__(256) void pv_k(const u16* __restrict__ Mb,
                                            const u8* __restrict__ Mask,
                                            const float* __restrict__ Rm,
                                            const float* __restrict__ Rz,
                                            const u16* __restrict__ VT,
                                            u16* __restrict__ Y) {
  const int cblk = blockIdx.x, tt = blockIdx.y, b = blockIdx.z;
  const int t0 = tt << 6, c0 = cblk << 6;
  __shared__ u16 Ps[NB_][64][32];
  __shared__ u16 Vs[NB_][64][32];
  const int tid = threadIdx.x;
  const int wave = tid >> 6, lane = tid & 63;
  const int row = tid & 63, s8 = (tid >> 6) << 3;
  const int lrow = lane & 15, lk = (lane >> 4) << 3;
  const int tg = t0 + row;
  const float rm = Rm[(b << 11) + tg];
  const float rz = Rz[(b << 11) + tg];
  const f32x4 zero = {0.f, 0.f, 0.f, 0.f};
  f32x4 acc[4] = {zero, zero, zero, zero};
  const size_t mrow0 = (size_t)b * T_ * T_ + (size_t)tg * T_;
  const int nchunk = (tt + 1) << 1;
  for (int ck = 0; ck < nchunk; ++ck) {
    const int sB = ck << 5;
    const ushort4 mu0 = *(const ushort4*)(Mb + mrow0 + sB + s8);
    const ushort4 mu1 = *(const ushort4*)(Mb + mrow0 + sB + s8 + 4);
    const uint2 mk2 = *(const uint2*)(Mask + mrow0 + sB + s8);
    float mvals[8] = {bf2f(mu0.x), bf2f(mu0.y), bf2f(mu0.z), bf2f(mu0.w),
                      bf2f(mu1.x), bf2f(mu1.y), bf2f(mu1.z), bf2f(mu1.w)};
    u16 pb[8];
#pragma unroll
    for (int j = 0; j < 8; ++j) pb[j] = f2bf(expf(mvals[j] - rm) * rz);
    u8 mk[8];
    mk[0] = mk2.x & 255; mk[1] = (mk2.x >> 8) & 255;
    mk[2] = (mk2.x >> 16) & 255; mk[3] = (mk2.x >> 24) & 255;
    mk[4] = mk2.y & 255; mk[5] = (mk2.y >> 8) & 255;
    mk[6] = (mk2.y >> 16) & 255; mk[7] = (mk2.y >> 24) & 255;
#pragma unroll
    for (int n = 0; n < NB_; ++n) {
      uint4 wv;
      wv.x = (unsigned)(((mk[0] >> n) & 1) ? pb[0] : 0) |
             ((unsigned)(((mk[1] >> n) & 1) ? pb[1] : 0) << 16);
      wv.y = (unsigned)(((mk[2] >> n) & 1) ? pb[2] : 0) |
             ((unsigned)(((mk[3] >> n) & 1) ? pb[3] : 0) << 16);
      wv.z = (unsigned)(((mk[4] >> n) & 1) ? pb[4] : 0) |
             ((unsigned)(((mk[5] >> n) & 1) ? pb[5] : 0) << 16);
      wv.w = (unsigned)(((mk[6] >> n) & 1) ? pb[6] : 0) |
             ((unsigned)(((mk[7] >> n) & 1) ? pb[7] : 0) << 16);
      *(uint4*)(&Ps[n][row][s8]) = wv;
      *(uint4*)(&Vs[n][row][s8]) = *(const uint4*)(
          &VT[((size_t)((b * NB_ + n) * C_ + c0 + row)) * T_ + sB + s8]);
    }
    __syncthreads();
#pragma unroll
    for (int n = 0; n < NB_; ++n) {
      short8 af = *(const short8*)(&Ps[n][(wave << 4) + lrow][lk]);
#pragma unroll
      for (int cs = 0; cs < 4; ++cs) {
        short8 bf = *(const short8*)(&Vs[n][(cs << 4) + lrow][lk]);
        acc[cs] = mfma16x16x32(af, bf, acc[cs]);
      }
    }
    __syncthreads();
  }
  const int tb = t0 + (wave << 4) + ((lane >> 4) << 2);
  const int cbs = c0 + (lane & 15);
#pragma unroll
  for (int cs = 0; cs < 4; ++cs) {
#pragma unroll
    for (int r = 0; r < 4; ++r) {
      Y[(size_t)((b << 11) + tb + r) * C_ + cbs + (cs << 4)] = f2bf(acc[cs][r]);
    }
  }
}

// ---------------------------------------------------------------------------
extern "C" void kernel_launch(void* const* d_in, const int* in_sizes, int n_in,
                              void* d_out, int out_size, void* d_ws,
                              size_t ws_size, hipStream_t stream) {
  (void)in_sizes; (void)n_in; (void)out_size; (void)ws_size;
  const float* a    = (const float*)d_in[0];
  const float* x    = (const float*)d_in[1];
  const float* Wq   = (const float*)d_in[2];
  const float* Wk   = (const float*)d_in[3];
  const float* Wv   = (const float*)d_in[4];
  const float* Wo   = (const float*)d_in[5];
  const float* cosT = (const float*)d_in[6];
  const float* sinT = (const float*)d_in[7];

  char* w = (char*)d_ws;
  u16* Qcat = (u16*)(w + 0);           // 33.5MB -> first 4.2MB reused as Y
  u16* Kcat = (u16*)(w + 33554432);    //  8.4MB
  u16* Vraw = (u16*)(w + 41943040);    // 16.8MB -> reused as bf16 M
  u16* VT   = (u16*)(w + 58720256);    // 16.8MB
  u8*  Mask = (u8*)(w + 75497472);     //  8.4MB
  float* Rm = (float*)(w + 83886080);  //  16KB
  float* Rz = (float*)(w + 83902464);  //  16KB  (end: 83,918,848)
  u16* Mb   = Vraw;
  u16* Y    = Qcat;

  const dim3 blk(256);
  gemm_qk<1><<<dim3(32, 64), blk, 0, stream>>>(a, Wq, Qcat, cosT, sinT, 2048, 512);
  gemm_qk<2><<<dim3(8, 64), blk, 0, stream>>>(x, Wk, Kcat, cosT, sinT, 512, 512);
  gemm_hi<1, 0><<<dim3(32, 64), blk, 0, stream>>>(a, Wv, (void*)Vraw, 2048, 512);
  transpose_v_k<<<dim3(2048), blk, 0, stream>>>(Vraw, VT);
  scores_k<<<dim3(32, 32, 2), blk, 0, stream>>>(Qcat, Kcat, Mb, Mask);
  rowstats_k<<<dim3(1024), blk, 0, stream>>>(Mb, Rm, Rz);
  pv_k<<<dim3(8, 32, 2), blk, 0, stream>>>(Mb, Mask, Rm, Rz, VT, Y);
  gemm_hi<0, 1><<<dim3(8, 64), blk, 0, stream>>>(Y, Wo, d_out, 512, 512);
}

// Round 8
// 464.177 us; speedup vs baseline: 4.8755x; 1.5977x over previous
//
#include <hip/hip_runtime.h>
#include <math.h>

// ============================================================================
// R8: attack scores_k (was 340us, MfmaUtil 6%, SQ_LDS_BANK_CONFLICT 3.1e7).
// * Conflict-free LDS staging in all MFMA kernels: writes remapped from
//   (row=tid&63, col=wave*8) [32-way write conflicts: wave writes a 16B
//   column across rows with 64B row stride] to (row=tid>>2, col=(tid&3)*8)
//   [address = tid*16B, perfectly linear].
// * scores_k: 3 split segments fused into one K-loop staging Qh/Ql x4 + Kh/Kl
//   (40KB LDS): 48 MFMA per barrier-pair (was 16), 32 barriers (was 96).
// * scores_k grid: triangular-packed (528,B) - no dead blocks.
// Numerics identical to R7 (absmax 0.015625 expected unchanged).
// ============================================================================

#define B_ 2
#define T_ 2048
#define C_ 512
#define NB_ 4
#define C2_ 1024  // hi|lo row width for Qcat/Kcat

typedef unsigned short u16;
typedef unsigned char u8;
using short8 = __attribute__((ext_vector_type(8))) short;
using bf16x8 = __attribute__((ext_vector_type(8))) __bf16;
using f32x4  = __attribute__((ext_vector_type(4))) float;

__device__ __forceinline__ float bf2f(u16 u) {
  union { unsigned int i; float f; } v; v.i = ((unsigned int)u) << 16; return v.f;
}
__device__ __forceinline__ u16 f2bf(float f) {  // round-to-nearest-even
  union { float f; unsigned int i; } v; v.f = f;
  unsigned int u = v.i;
  return (u16)((u + 0x7fffu + ((u >> 16) & 1u)) >> 16);
}
__device__ __forceinline__ f32x4 mfma16x16x32(short8 a, short8 b, f32x4 c) {
  return __builtin_amdgcn_mfma_f32_16x16x32_bf16(
      __builtin_bit_cast(bf16x8, a), __builtin_bit_cast(bf16x8, b), c, 0, 0, 0);
}
__device__ __forceinline__ void split8(const float* s, uint4& hi, uint4& lo) {
  u16 h[8], l[8];
#pragma unroll
  for (int j = 0; j < 8; ++j) {
    h[j] = f2bf(s[j]);
    l[j] = f2bf(s[j] - bf2f(h[j]));
  }
  hi.x = h[0] | ((unsigned)h[1] << 16); hi.y = h[2] | ((unsigned)h[3] << 16);
  hi.z = h[4] | ((unsigned)h[5] << 16); hi.w = h[6] | ((unsigned)h[7] << 16);
  lo.x = l[0] | ((unsigned)l[1] << 16); lo.y = l[2] | ((unsigned)l[3] << 16);
  lo.z = l[4] | ((unsigned)l[5] << 16); lo.w = l[6] | ((unsigned)l[7] << 16);
}

// ---------------------------------------------------------------------------
// Split-precision 64x64 GEMM with fused RoPE epilogue.
// MODE 1: +1/sqrt(C) scale -> Qcat (B,NB,T,[hi512|lo512]).
// MODE 2: -> Kcat (B*T,[hi512|lo512]).
// ---------------------------------------------------------------------------
template <int MODE>
__global__ __launch_bounds__(256) void gemm_qk(const float* __restrict__ A,
                                               const float* __restrict__ W,
                                               u16* __restrict__ out,
                                               const float* __restrict__ cosT,
                                               const float* __restrict__ sinT,
                                               const int N, const int K) {
  __shared__ u16 Ah[64][32], Al[64][32];
  __shared__ u16 Bh[64][32], Bl[64][32];  // [n][k]
  const int tid = threadIdx.x;
  const int wave = tid >> 6, lane = tid & 63;
  const int m0 = blockIdx.y << 6, n0 = blockIdx.x << 6;
  const f32x4 zero = {0.f, 0.f, 0.f, 0.f};
  f32x4 acc[4] = {zero, zero, zero, zero};
  const int srow = tid >> 2, koff = (tid & 3) << 3;  // linear LDS staging
  const int lrow = lane & 15, lk = (lane >> 4) << 3;
  for (int kk = 0; kk < K; kk += 32) {
    float av[8];
    *(float4*)(av) = *(const float4*)(&A[(size_t)(m0 + srow) * K + kk + koff]);
    *(float4*)(av + 4) =
        *(const float4*)(&A[(size_t)(m0 + srow) * K + kk + koff + 4]);
    uint4 hi, lo;
    split8(av, hi, lo);
    *(uint4*)(&Ah[srow][koff]) = hi;
    *(uint4*)(&Al[srow][koff]) = lo;
    float wv[8];
#pragma unroll
    for (int j = 0; j < 8; ++j)
      wv[j] = W[(size_t)(kk + koff + j) * N + n0 + srow];
    split8(wv, hi, lo);
    *(uint4*)(&Bh[srow][koff]) = hi;
    *(uint4*)(&Bl[srow][koff]) = lo;
    __syncthreads();
    short8 ah = *(const short8*)(&Ah[(wave << 4) + lrow][lk]);
    short8 al = *(const short8*)(&Al[(wave << 4) + lrow][lk]);
#pragma unroll
    for (int ns = 0; ns < 4; ++ns) {
      short8 bh = *(const short8*)(&Bh[(ns << 4) + lrow][lk]);
      short8 bl = *(const short8*)(&Bl[(ns << 4) + lrow][lk]);
      acc[ns] = mfma16x16x32(ah, bh, acc[ns]);
      acc[ns] = mfma16x16x32(al, bh, acc[ns]);
      acc[ns] = mfma16x16x32(ah, bl, acc[ns]);
    }
    __syncthreads();
  }
  const int r0 = m0 + (wave << 4) + ((lane >> 4) << 2);
  const int cb = n0 + (lane & 15);
#pragma unroll
  for (int ns = 0; ns < 4; ++ns) {
#pragma unroll
    for (int r = 0; r < 4; ++r) {
      const int rg = r0 + r;
      const int cg = cb + (ns << 4);
      float v = acc[ns][r];
      float pv = __shfl_xor(v, 1);  // partner column of the RoPE pair
      const int t = rg & (T_ - 1);
      const int c = (MODE == 1) ? (cg & (C_ - 1)) : cg;
      const int i = c >> 1;
      const float cf = cosT[(t << 8) + i];
      const float sf = sinT[(t << 8) + i];
      float x1 = (lane & 1) ? pv : v;
      float x2 = (lane & 1) ? v : pv;
      float y = (lane & 1) ? (x1 * sf + x2 * cf) : (x1 * cf - x2 * sf);
      if (MODE == 1) y *= 0.044194173824159216f;  // 1/sqrt(512)
      const u16 hi = f2bf(y);
      const u16 lo = f2bf(y - bf2f(hi));
      size_t rowoff;
      if (MODE == 1) {
        const int b = rg >> 11, n = cg >> 9;
        rowoff = ((size_t)((b * NB_ + n) * T_ + t)) * C2_;
      } else {
        rowoff = (size_t)rg * C2_;
      }
      out[rowoff + c] = hi;
      out[rowoff + C_ + c] = lo;
    }
  }
}

// ---------------------------------------------------------------------------
// Plain hi-only GEMM: A f32 (AF32=1) or bf16, W f32; out bf16 or f32 (OF32).
// ---------------------------------------------------------------------------
template <int AF32, int OF32>
__global__ __launch_bounds__(256) void gemm_hi(const void* __restrict__ Ap,
                                               const float* __restrict__ W,
                                               void* __restrict__ outp,
                                               const int N, const int K) {
  __shared__ u16 As[64][32];
  __shared__ u16 Bs[64][32];
  const int tid = threadIdx.x;
  const int wave = tid >> 6, lane = tid & 63;
  const int m0 = blockIdx.y << 6, n0 = blockIdx.x << 6;
  const f32x4 zero = {0.f, 0.f, 0.f, 0.f};
  f32x4 acc[4] = {zero, zero, zero, zero};
  const int srow = tid >> 2, koff = (tid & 3) << 3;  // linear LDS staging
  const int lrow = lane & 15, lk = (lane >> 4) << 3;
  for (int kk = 0; kk < K; kk += 32) {
    if (AF32) {
      const float* A = (const float*)Ap;
      float av[8];
      *(float4*)(av) = *(const float4*)(&A[(size_t)(m0 + srow) * K + kk + koff]);
      *(float4*)(av + 4) =
          *(const float4*)(&A[(size_t)(m0 + srow) * K + kk + koff + 4]);
      uint4 hi;
      hi.x = f2bf(av[0]) | ((unsigned)f2bf(av[1]) << 16);
      hi.y = f2bf(av[2]) | ((unsigned)f2bf(av[3]) << 16);
      hi.z = f2bf(av[4]) | ((unsigned)f2bf(av[5]) << 16);
      hi.w = f2bf(av[6]) | ((unsigned)f2bf(av[7]) << 16);
      *(uint4*)(&As[srow][koff]) = hi;
    } else {
      const u16* A = (const u16*)Ap;
      *(uint4*)(&As[srow][koff]) =
          *(const uint4*)(&A[(size_t)(m0 + srow) * K + kk + koff]);
    }
    uint4 hi;
    {
      float w[8];
#pragma unroll
      for (int j = 0; j < 8; ++j)
        w[j] = W[(size_t)(kk + koff + j) * N + n0 + srow];
      hi.x = f2bf(w[0]) | ((unsigned)f2bf(w[1]) << 16);
      hi.y = f2bf(w[2]) | ((unsigned)f2bf(w[3]) << 16);
      hi.z = f2bf(w[4]) | ((unsigned)f2bf(w[5]) << 16);
      hi.w = f2bf(w[6]) | ((unsigned)f2bf(w[7]) << 16);
    }
    *(uint4*)(&Bs[srow][koff]) = hi;
    __syncthreads();
    short8 af = *(const short8*)(&As[(wave << 4) + lrow][lk]);
#pragma unroll
    for (int ns = 0; ns < 4; ++ns) {
      short8 bf = *(const short8*)(&Bs[(ns << 4) + lrow][lk]);
      acc[ns] = mfma16x16x32(af, bf, acc[ns]);
    }
    __syncthreads();
  }
  const int r0 = m0 + (wave << 4) + ((lane >> 4) << 2);
  const int cb = n0 + (lane & 15);
#pragma unroll
  for (int ns = 0; ns < 4; ++ns) {
#pragma unroll
    for (int r = 0; r < 4; ++r) {
      const size_t idx = (size_t)(r0 + r) * N + cb + (ns << 4);
      if (OF32) ((float*)outp)[idx] = acc[ns][r];
      else ((u16*)outp)[idx] = f2bf(acc[ns][r]);
    }
  }
}

// ---------------------------------------------------------------------------
// Vraw (B,T,NB*C) bf16 -> VT (B,NB,C,T) tiled transpose, 64x64 tiles.
// ---------------------------------------------------------------------------
__global__ __launch_bounds__(256) void transpose_v_k(const u16* __restrict__ Vraw,
                                                     u16* __restrict__ VT) {
  const int bid = blockIdx.x;
  const int ct = bid & 7;
  const int ttile = (bid >> 3) & 31;
  const int n = (bid >> 8) & 3;
  const int b = bid >> 10;
  __shared__ u16 tile[64][68];
  const int tid = threadIdx.x;
  const int rr = tid >> 4;
  const int cc = (tid & 15) << 2;
  const int t0 = ttile << 6, c0 = ct << 6;
#pragma unroll
  for (int it = 0; it < 4; ++it) {
    const int r = (it << 4) + rr;
    *(ushort4*)(&tile[r][cc]) = *(const ushort4*)(
        &Vraw[((size_t)((b << 11) + t0 + r)) * (NB_ * C_) + n * C_ + c0 + cc]);
  }
  __syncthreads();
#pragma unroll
  for (int it = 0; it < 4; ++it) {
    const int c = (it << 4) + rr;
    ushort4 w;
    w.x = tile[cc + 0][c]; w.y = tile[cc + 1][c];
    w.z = tile[cc + 2][c]; w.w = tile[cc + 3][c];
    *(ushort4*)(&VT[((size_t)((b * NB_ + n) * C_ + c0 + c)) * T_ + t0 + cc]) = w;
  }
}

// ---------------------------------------------------------------------------
// Scores: per lower-tri 64x64 (t,s) tile (triangular-packed grid), 4 branches,
// fused split segments: stage Qh/Ql x4 + Kh/Kl per 32-K chunk (40KB LDS),
// acc = qh.kh + ql.kh + qh.kl. Branch max + multi-hot tie mask from f32 acc,
// causal -inf. Writes M (bf16) and Mask (u8).
// ---------------------------------------------------------------------------
__global__ __launch_bounds__(256) void scores_k(const u16* __restrict__ Qcat,
                                                const u16* __restrict__ Kcat,
                                                u16* __restrict__ Mout,
                                                u8* __restrict__ Mask) {
  const int tri = blockIdx.x;
  int tt = (int)((sqrtf(8.f * (float)tri + 1.f) - 1.f) * 0.5f);
  while ((tt + 1) * (tt + 2) / 2 <= tri) ++tt;
  while (tt * (tt + 1) / 2 > tri) --tt;
  const int ss = tri - tt * (tt + 1) / 2;
  const int b = blockIdx.y;
  __shared__ u16 Qh[NB_][64][32], Ql[NB_][64][32];
  __shared__ u16 Kh[64][32], Kl[64][32];
  const int tid = threadIdx.x;
  const int wave = tid >> 6, lane = tid & 63;
  const int t0 = tt << 6, s0 = ss << 6;
  const f32x4 zero = {0.f, 0.f, 0.f, 0.f};
  f32x4 acc[NB_][4];
  for (int n = 0; n < NB_; ++n)
    for (int j = 0; j < 4; ++j) acc[n][j] = zero;
  const int srow = tid >> 2, koff = (tid & 3) << 3;  // linear LDS staging
  const int lrow = lane & 15, lk = (lane >> 4) << 3;
  for (int kk = 0; kk < C_; kk += 32) {
#pragma unroll
    for (int n = 0; n < NB_; ++n) {
      const size_t qb =
          ((size_t)((b * NB_ + n) * T_ + t0 + srow)) * C2_ + kk + koff;
      *(uint4*)(&Qh[n][srow][koff]) = *(const uint4*)(&Qcat[qb]);
      *(uint4*)(&Ql[n][srow][koff]) = *(const uint4*)(&Qcat[qb + C_]);
    }
    const size_t kb = ((size_t)((b << 11) + s0 + srow)) * C2_ + kk + koff;
    *(uint4*)(&Kh[srow][koff]) = *(const uint4*)(&Kcat[kb]);
    *(uint4*)(&Kl[srow][koff]) = *(const uint4*)(&Kcat[kb + C_]);
    __syncthreads();
    short8 qh[NB_], ql[NB_];
#pragma unroll
    for (int n = 0; n < NB_; ++n) {
      qh[n] = *(const short8*)(&Qh[n][(wave << 4) + lrow][lk]);
      ql[n] = *(const short8*)(&Ql[n][(wave << 4) + lrow][lk]);
    }
#pragma unroll
    for (int ns = 0; ns < 4; ++ns) {
      short8 kh = *(const short8*)(&Kh[(ns << 4) + lrow][lk]);
      short8 kl = *(const short8*)(&Kl[(ns << 4) + lrow][lk]);
#pragma unroll
      for (int n = 0; n < NB_; ++n) {
        acc[n][ns] = mfma16x16x32(qh[n], kh, acc[n][ns]);
        acc[n][ns] = mfma16x16x32(ql[n], kh, acc[n][ns]);
        acc[n][ns] = mfma16x16x32(qh[n], kl, acc[n][ns]);
      }
    }
    __syncthreads();
  }
  const int tb = t0 + (wave << 4) + ((lane >> 4) << 2);
  const int sb = s0 + (lane & 15);
#pragma unroll
  for (int ns = 0; ns < 4; ++ns) {
#pragma unroll
    for (int r = 0; r < 4; ++r) {
      const int t = tb + r, s = sb + (ns << 4);
      float a0 = acc[0][ns][r], a1 = acc[1][ns][r];
      float a2 = acc[2][ns][r], a3 = acc[3][ns][r];
      float m = fmaxf(fmaxf(a0, a1), fmaxf(a2, a3));
      u8 msk = (u8)((a0 == m) | ((a1 == m) << 1) | ((a2 == m) << 2) |
                    ((a3 == m) << 3));
      if (s > t) { m = -__builtin_inff(); msk = 0; }
      const size_t idx = (size_t)b * T_ * T_ + (size_t)t * T_ + s;
      Mout[idx] = f2bf(m);
      Mask[idx] = msk;
    }
  }
}

// ---------------------------------------------------------------------------
// Per-row softmax stats from bf16 M: rowmax, 1/sum(exp). One wave per (b,t).
// ---------------------------------------------------------------------------
__global__ __launch_bounds__(256) void rowstats_k(const u16* __restrict__ Mb,
                                                  float* __restrict__ Rm,
                                                  float* __restrict__ Rz) {
  const int r = (blockIdx.x << 2) + (threadIdx.x >> 6);
  const int lane = threadIdx.x & 63;
  const int b = r >> 11, t = r & (T_ - 1);
  const u16* row = Mb + (size_t)b * T_ * T_ + (size_t)t * T_;
  float m = -__builtin_inff();
  for (int s = lane; s <= t; s += 64) m = fmaxf(m, bf2f(row[s]));
#pragma unroll
  for (int off = 32; off; off >>= 1) m = fmaxf(m, __shfl_xor(m, off));
  float z = 0.f;
  for (int s = lane; s <= t; s += 64) z += expf(bf2f(row[s]) - m);
#pragma unroll
  for (int off = 32; off; off >>= 1) z += __shfl_xor(z, off);
  if (lane == 0) { Rm[r] = m; Rz[r] = 1.f / z; }
}

// ---------------------------------------------------------------------------
// Routed PV: y = sum_n P_n @ V_n with per-branch masked P built in LDS from
// bf16 M + mask. 64 t-rows x 64 c-cols per block, causal s-chunks of 32.
// Staging remapped to linear (prow = tid>>2, soff = (tid&3)*8).
// ---------------------------------------------------------------------------
__global__ __launch_bounds__(256) void pv_k(const u16* __restrict__ Mb,
                                            const u8* __restrict__ Mask,
                                            const float* __restrict__ Rm,
                                            const float* __restrict__ Rz,
                                            const u16* __restrict__ VT,
                                            u16* __restrict__ Y) {
  const int cblk = blockIdx.x, tt = blockIdx.y, b = blockIdx.z;
  const int t0 = tt << 6, c0 = cblk << 6;
  __shared__ u16 Ps[NB_][64][32];
  __shared__ u16 Vs[NB_][64][32];
  const int tid = threadIdx.x;
  const int wave = tid >> 6, lane = tid & 63;
  const int prow = tid >> 2, soff = (tid & 3) << 3;  // linear LDS staging
  const int lrow = lane & 15, lk = (lane >> 4) << 3;
  const int tg = t0 + prow;
  const float rm = Rm[(b << 11) + tg];
  const float rz = Rz[(b << 11) + tg];
  const f32x4 zero = {0.f, 0.f, 0.f, 0.f};
  f32x4 acc[4] = {zero, zero, zero, zero};
  const size_t mrow0 = (size_t)b * T_ * T_ + (size_t)tg * T_;
  const int nchunk = (tt + 1) << 1;
  for (int ck = 0; ck < nchunk; ++ck) {
    const int sB = ck << 5;
    const ushort4 mu0 = *(const ushort4*)(Mb + mrow0 + sB + soff);
    const ushort4 mu1 = *(const ushort4*)(Mb + mrow0 + sB + soff + 4);
    const uint2 mk2 = *(const uint2*)(Mask + mrow0 + sB + soff);
    float mvals[8] = {bf2f(mu0.x), bf2f(mu0.y), bf2f(mu0.z), bf2f(mu0.w),
                      bf2f(mu1.x), bf2f(mu1.y), bf2f(mu1.z), bf2f(mu1.w)};
    u16 pb[8];
#pragma unroll
    for (int j = 0; j < 8; ++j) pb[j] = f2bf(expf(mvals[j] - rm) * rz);
    u8 mk[8];
    mk[0] = mk2.x & 255; mk[1] = (mk2.x >> 8) & 255;
    mk[2] = (mk2.x >> 16) & 255; mk[3] = (mk2.x >> 24) & 255;
    mk[4] = mk2.y & 255; mk[5] = (mk2.y >> 8) & 255;
    mk[6] = (mk2.y >> 16) & 255; mk[7] = (mk2.y >> 24) & 255;
#pragma unroll
    for (int n = 0; n < NB_; ++n) {
      uint4 wv;
      wv.x = (unsigned)(((mk[0] >> n) & 1) ? pb[0] : 0) |
             ((unsigned)(((mk[1] >> n) & 1) ? pb[1] : 0) << 16);
      wv.y = (unsigned)(((mk[2] >> n) & 1) ? pb[2] : 0) |
             ((unsigned)(((mk[3] >> n) & 1) ? pb[3] : 0) << 16);
      wv.z = (unsigned)(((mk[4] >> n) & 1) ? pb[4] : 0) |
             ((unsigned)(((mk[5] >> n) & 1) ? pb[5] : 0) << 16);
      wv.w = (unsigned)(((mk[6] >> n) & 1) ? pb[6] : 0) |
             ((unsigned)(((mk[7] >> n) & 1) ? pb[7] : 0) << 16);
      *(uint4*)(&Ps[n][prow][soff]) = wv;
      *(uint4*)(&Vs[n][prow][soff]) = *(const uint4*)(
          &VT[((size_t)((b * NB_ + n) * C_ + c0 + prow)) * T_ + sB + soff]);
    }
    __syncthreads();
#pragma unroll
    for (int n = 0; n < NB_; ++n) {
      short8 af = *(const short8*)(&Ps[n][(wave << 4) + lrow][lk]);
#pragma unroll
      for (int cs = 0; cs < 4; ++cs) {
        short8 bf = *(const short8*)(&Vs[n][(cs << 4) + lrow][lk]);
        acc[cs] = mfma16x16x32(af, bf, acc[cs]);
      }
    }
    __syncthreads();
  }
  const int tb = t0 + (wave << 4) + ((lane >> 4) << 2);
  const int cbs = c0 + (lane & 15);
#pragma unroll
  for (int cs = 0; cs < 4; ++cs) {
#pragma unroll
    for (int r = 0; r < 4; ++r) {
      Y[(size_t)((b << 11) + tb + r) * C_ + cbs + (cs << 4)] = f2bf(acc[cs][r]);
    }
  }
}

// ---------------------------------------------------------------------------
extern "C" void kernel_launch(void* const* d_in, const int* in_sizes, int n_in,
                              void* d_out, int out_size, void* d_ws,
                              size_t ws_size, hipStream_t stream) {
  (void)in_sizes; (void)n_in; (void)out_size; (void)ws_size;
  const float* a    = (const float*)d_in[0];
  const float* x    = (const float*)d_in[1];
  const float* Wq   = (const float*)d_in[2];
  const float* Wk   = (const float*)d_in[3];
  const float* Wv   = (const float*)d_in[4];
  const float* Wo   = (const float*)d_in[5];
  const float* cosT = (const float*)d_in[6];
  const float* sinT = (const float*)d_in[7];

  char* w = (char*)d_ws;
  u16* Qcat = (u16*)(w + 0);           // 33.5MB -> first 4.2MB reused as Y
  u16* Kcat = (u16*)(w + 33554432);    //  8.4MB
  u16* Vraw = (u16*)(w + 41943040);    // 16.8MB -> reused as bf16 M
  u16* VT   = (u16*)(w + 58720256);    // 16.8MB
  u8*  Mask = (u8*)(w + 75497472);     //  8.4MB
  float* Rm = (float*)(w + 83886080);  //  16KB
  float* Rz = (float*)(w + 83902464);  //  16KB  (end: 83,918,848)
  u16* Mb   = Vraw;
  u16* Y    = Qcat;

  const dim3 blk(256);
  gemm_qk<1><<<dim3(32, 64), blk, 0, stream>>>(a, Wq, Qcat, cosT, sinT, 2048, 512);
  gemm_qk<2><<<dim3(8, 64), blk, 0, stream>>>(x, Wk, Kcat, cosT, sinT, 512, 512);
  gemm_hi<1, 0><<<dim3(32, 64), blk, 0, stream>>>(a, Wv, (void*)Vraw, 2048, 512);
  transpose_v_k<<<dim3(2048), blk, 0, stream>>>(Vraw, VT);
  scores_k<<<dim3(528, 2), blk, 0, stream>>>(Qcat, Kcat, Mb, Mask);
  rowstats_k<<<dim3(1024), blk, 0, stream>>>(Mb, Rm, Rz);
  pv_k<<<dim3(8, 32, 2), blk, 0, stream>>>(Mb, Mask, Rm, Rz, VT, Y);
  gemm_hi<0, 1><<<dim3(8, 64), blk, 0, stream>>>(Y, Wo, d_out, 512, 512);
}